// Round 5
// baseline (474.567 us; speedup 1.0000x reference)
//
#include <hip/hip_runtime.h>
#include <hip/hip_bf16.h>
#include <cstdint>
#include <cstddef>

#define NQ      14
#define SDIM    16384          // 1 << NQ
#define NGATES  39             // 3 layers * 13 sparse two-qubit chain gates
#define NBATCH  1024

// ---------------------------------------------------------------------------
// helpers
// ---------------------------------------------------------------------------
__device__ __forceinline__ int swz(int i) { return i ^ ((i >> 4) & 15); }

__device__ __forceinline__ float2 cmul(float2 a, float2 b) {
    return make_float2(fmaf(a.x, b.x, -a.y * b.y), fmaf(a.x, b.y, a.y * b.x));
}
__device__ __forceinline__ void cfma(float2 &o, float2 a, float2 b) {
    o.x = fmaf(a.x, b.x, fmaf(-a.y, b.y, o.x));
    o.y = fmaf(a.x, b.y, fmaf( a.y, b.x, o.y));
}

__device__ void mm2(const float2 A[2][2], const float2 B[2][2], float2 C[2][2]) {
    #pragma unroll
    for (int i = 0; i < 2; ++i)
        #pragma unroll
        for (int j = 0; j < 2; ++j) {
            float2 t = cmul(A[i][0], B[0][j]);
            cfma(t, A[i][1], B[1][j]);
            C[i][j] = t;
        }
}

// U = RZ(g) * RY(b) * RX(a)  (optionally right-multiplied by encoding RY for layer 0)
__device__ void build_u(const float* __restrict__ rp, const float* __restrict__ enc,
                        int l, int q, float2 U[2][2]) {
    const float* p = rp + (l * NQ + q) * 3;
    float ha = 0.5f * p[0], hb = 0.5f * p[1], hg = 0.5f * p[2];
    float cx = cosf(ha), sx = sinf(ha);
    float cy = cosf(hb), sy = sinf(hb);
    float cz = cosf(hg), sz = sinf(hg);
    float2 RX[2][2] = { { make_float2(cx, 0.f), make_float2(0.f, -sx) },
                        { make_float2(0.f, -sx), make_float2(cx, 0.f) } };
    float2 RY[2][2] = { { make_float2(cy, 0.f), make_float2(-sy, 0.f) },
                        { make_float2(sy, 0.f), make_float2(cy, 0.f) } };
    float2 W[2][2];
    mm2(RY, RX, W);
    float2 zl = make_float2(cz, -sz), zh = make_float2(cz, sz);
    float2 V[2][2];
    V[0][0] = cmul(zl, W[0][0]); V[0][1] = cmul(zl, W[0][1]);
    V[1][0] = cmul(zh, W[1][0]); V[1][1] = cmul(zh, W[1][1]);
    if (l == 0) {   // encoding RY applied BEFORE layer-0 rotations -> right-multiply
        float he = 0.5f * enc[q];
        float ce = cosf(he), se = sinf(he);
        float2 RE[2][2] = { { make_float2(ce, 0.f), make_float2(-se, 0.f) },
                            { make_float2(se, 0.f), make_float2(ce, 0.f) } };
        mm2(V, RE, U);
    } else {
        U[0][0] = V[0][0]; U[0][1] = V[0][1];
        U[1][0] = V[1][0]; U[1][1] = V[1][1];
    }
}

// ---------------------------------------------------------------------------
// Sparse chain-gate on the 4-qubit register window. Gate jj acts on qubits
// (jj, jj+1) = local bits (CP, CP+1); basis j = (t<<1)|c with c = bit CP.
// 8 stored coeffs: [c0 block: m00,m01,m10,m11][c1 block: m00,m01,m10,m11].
// Coeffs loaded per half-block at point of use; sched_barrier keeps the
// scheduler from hoisting all loads (register-pressure fence — the r2-r4
// allocator pins VGPR=64, so peak live set must stay under it).
// ---------------------------------------------------------------------------
template<int CP>
__device__ __forceinline__ void gate_sparse8(float2 v[16], const float2* __restrict__ G) {
    {
        float2 c00 = G[0], c01 = G[1], c10 = G[2], c11 = G[3];
        #pragma unroll
        for (int rr = 0; rr < 4; ++rr) {
            const int base = ((rr >> CP) << (CP + 2)) | (rr & ((1 << CP) - 1));
            const int m0 = base, m2 = base | (2 << CP);
            float2 a0 = v[m0], a2 = v[m2];
            float2 o0 = cmul(c00, a0); cfma(o0, c01, a2);
            float2 o2 = cmul(c10, a0); cfma(o2, c11, a2);
            v[m0] = o0; v[m2] = o2;
        }
    }
    __builtin_amdgcn_sched_barrier(0);
    {
        float2 c00 = G[4], c01 = G[5], c10 = G[6], c11 = G[7];
        #pragma unroll
        for (int rr = 0; rr < 4; ++rr) {
            const int base = ((rr >> CP) << (CP + 2)) | (rr & ((1 << CP) - 1));
            const int m1 = base | (1 << CP), m3 = base | (3 << CP);
            float2 a1 = v[m1], a3 = v[m3];
            float2 o1 = cmul(c00, a1); cfma(o1, c01, a3);
            float2 o3 = cmul(c10, a1); cfma(o3, c11, a3);
            v[m1] = o1; v[m3] = o3;
        }
    }
}

template<int AQ>
__device__ __forceinline__ int win_base(int tid) {
    return ((tid >> AQ) << (AQ + 4)) | (tid & ((1 << AQ) - 1));
}

// One LDS round-trip applying up to 3 chain gates (+ optional 2x2 U0 on bit0).
template<int AQ, bool INIT, bool WITH_U0>
__device__ __forceinline__ void passW(float2* __restrict__ st,
                                      const float2* __restrict__ gb,
                                      const float2* __restrict__ U0,
                                      int tid) {
    const int i0 = win_base<AQ>(tid);
    float2 v[16];
    if (INIT) {
        #pragma unroll
        for (int j = 0; j < 16; ++j) v[j] = make_float2(0.f, 0.f);
        if (tid == 0) v[0] = make_float2(1.f, 0.f);
    } else {
        #pragma unroll
        for (int j = 0; j < 16; ++j) v[j] = st[swz(i0 + (j << AQ))];
    }
    __builtin_amdgcn_sched_barrier(0);
    if (WITH_U0) {
        float2 u00 = U0[0], u01 = U0[1], u10 = U0[2], u11 = U0[3];
        #pragma unroll
        for (int k = 0; k < 8; ++k) {
            float2 e = v[2 * k], o = v[2 * k + 1];
            float2 ne = cmul(u00, e); cfma(ne, u01, o);
            float2 no = cmul(u10, e); cfma(no, u11, o);
            v[2 * k] = ne; v[2 * k + 1] = no;
        }
        __builtin_amdgcn_sched_barrier(0);
    }
    gate_sparse8<0>(v, gb);
    __builtin_amdgcn_sched_barrier(0);
    gate_sparse8<1>(v, gb + 8);
    __builtin_amdgcn_sched_barrier(0);
    gate_sparse8<2>(v, gb + 16);
    __builtin_amdgcn_sched_barrier(0);
    // recompute write addresses (anti-CSE: keeping 16 idx regs live across the
    // gates would blow the 64-VGPR budget and spill)
    int i0w = i0;
    asm volatile("" : "+v"(i0w));
    #pragma unroll
    for (int j = 0; j < 16; ++j) st[swz(i0w + (j << AQ))] = v[j];
}

// Final pass of a layer: gate 12 on qubits (12,13), window {10-13}, CP=2.
template<bool EMIT>
__device__ __forceinline__ void passLast(float2* __restrict__ st,
                                         const float2* __restrict__ gb,
                                         float* __restrict__ fr, int tid) {
    const int i0 = win_base<10>(tid);   // == tid for tid < 1024
    float2 v[16];
    #pragma unroll
    for (int j = 0; j < 16; ++j) v[j] = st[swz(i0 + (j << 10))];
    __builtin_amdgcn_sched_barrier(0);
    gate_sparse8<2>(v, gb);
    __builtin_amdgcn_sched_barrier(0);
    if (EMIT) {
        #pragma unroll
        for (int j = 0; j < 16; ++j)
            fr[i0 + (j << 10)] = fmaf(v[j].x, v[j].x, v[j].y * v[j].y);
    } else {
        int i0w = i0;
        asm volatile("" : "+v"(i0w));
        #pragma unroll
        for (int j = 0; j < 16; ++j) st[swz(i0w + (j << 10))] = v[j];
    }
}

// ---------------------------------------------------------------------------
// Kernel 1: full circuit simulation, one workgroup per batch element.
// State in LDS (128 KiB, XOR-swizzled). 15 register-window passes, all gates
// sparse (8 coeffs); per-layer U(q0) is a separate in-register 2x2.
// ---------------------------------------------------------------------------
__global__ __launch_bounds__(1024) __attribute__((amdgpu_waves_per_eu(4, 4)))
void sim_kernel(
    const float* __restrict__ x,     // (1024, 64)
    const float* __restrict__ ep,    // (64, 14)
    const float* __restrict__ rp,    // (3, 14, 3)
    const float* __restrict__ ent,   // (3, 13)
    float* __restrict__ feats)       // (1024, 16384)
{
    extern __shared__ char smem[];
    float2* st   = (float2*)smem;                                    // 131072 B
    float2* gmat = (float2*)(smem + 131072);                         // 39*8*8 = 2496 B
    float2* u0m  = (float2*)(smem + 131072 + NGATES * 8 * (int)sizeof(float2));  // 96 B
    float*  angles = (float*)(smem + 131072 + (NGATES * 8 + 12) * (int)sizeof(float2));

    const int tid = threadIdx.x;
    const int b   = blockIdx.x;

    // --- encoding angles: one wave per qubit, shuffle-reduce ---
    if (tid < 14 * 64) {
        const int q = tid >> 6, k = tid & 63;
        float p = x[(size_t)b * 64 + k] * ep[k * NQ + q];
        #pragma unroll
        for (int off = 32; off; off >>= 1) p += __shfl_down(p, off, 64);
        if (k == 0) angles[q] = p;
    }
    __syncthreads();

    // --- build gate tables: 39 sparse chain gates + 3 per-layer U(q0) ---
    if (tid < NGATES) {
        int l = tid / 13, jj = tid - l * 13;     // gate on qubits (jj, jj+1)
        float2 Ut[2][2];
        build_u(rp, angles, l, jj + 1, Ut);
        float th = ent[l * 13 + jj];
        float ct = cosf(th), s = sinf(th);
        float2* G = gmat + tid * 8;
        // c=0 block: pcnot inactive -> Ut itself
        G[0] = Ut[0][0]; G[1] = Ut[0][1]; G[2] = Ut[1][0]; G[3] = Ut[1][1];
        // c=1 block: rows mixed by cos(th) + i sin(th) * X_target
        G[4] = make_float2(fmaf(ct, Ut[0][0].x, -s * Ut[1][0].y), fmaf(ct, Ut[0][0].y, s * Ut[1][0].x));
        G[5] = make_float2(fmaf(ct, Ut[0][1].x, -s * Ut[1][1].y), fmaf(ct, Ut[0][1].y, s * Ut[1][1].x));
        G[6] = make_float2(fmaf(ct, Ut[1][0].x, -s * Ut[0][0].y), fmaf(ct, Ut[1][0].y, s * Ut[0][0].x));
        G[7] = make_float2(fmaf(ct, Ut[1][1].x, -s * Ut[0][1].y), fmaf(ct, Ut[1][1].y, s * Ut[0][1].x));
    } else if (tid < NGATES + 3) {
        int l = tid - NGATES;
        float2 U[2][2];
        build_u(rp, angles, l, 0, U);
        float2* D = u0m + l * 4;
        D[0] = U[0][0]; D[1] = U[0][1]; D[2] = U[1][0]; D[3] = U[1][1];
    }
    __syncthreads();

    float* fr = feats + (size_t)b * SDIM;

    // --- layer 0 (synthesized from |0..0>, no initial LDS read) ---
    {
        const float2* gl = gmat;
        passW<0, true,  true >(st, gl,          u0m,     tid); __syncthreads();
        passW<3, false, false>(st, gl + 3 * 8,  nullptr, tid); __syncthreads();
        passW<6, false, false>(st, gl + 6 * 8,  nullptr, tid); __syncthreads();
        passW<9, false, false>(st, gl + 9 * 8,  nullptr, tid); __syncthreads();
        passLast<false>(st, gl + 12 * 8, nullptr, tid);        __syncthreads();
    }
    // --- layer 1 ---
    {
        const float2* gl = gmat + 13 * 8;
        passW<0, false, true >(st, gl,          u0m + 4, tid); __syncthreads();
        passW<3, false, false>(st, gl + 3 * 8,  nullptr, tid); __syncthreads();
        passW<6, false, false>(st, gl + 6 * 8,  nullptr, tid); __syncthreads();
        passW<9, false, false>(st, gl + 9 * 8,  nullptr, tid); __syncthreads();
        passLast<false>(st, gl + 12 * 8, nullptr, tid);        __syncthreads();
    }
    // --- layer 2 (final pass emits |amp|^2 straight to global) ---
    {
        const float2* gl = gmat + 26 * 8;
        passW<0, false, true >(st, gl,          u0m + 8, tid); __syncthreads();
        passW<3, false, false>(st, gl + 3 * 8,  nullptr, tid); __syncthreads();
        passW<6, false, false>(st, gl + 6 * 8,  nullptr, tid); __syncthreads();
        passW<9, false, false>(st, gl + 9 * 8,  nullptr, tid); __syncthreads();
        passLast<true>(st, gl + 12 * 8, fr, tid);
    }
}

// ---------------------------------------------------------------------------
// Kernel 2: GEMM1 partials: part[bz] = feats[:, bz-chunk] @ w1[bz-chunk, :]
// M=1024, N=256, K=16384 split 8 ways. 64x64 tile, 4x4 per-thread regs.
// ---------------------------------------------------------------------------
__global__ __launch_bounds__(256) void gemm1_kernel(
    const float* __restrict__ feats,   // (1024, 16384)
    const float* __restrict__ w1,      // (16384, 256)
    float* __restrict__ part)          // (8, 1024, 256)
{
    __shared__ float As[16][68];
    __shared__ float Bs[16][68];
    const int tx = threadIdx.x & 15, ty = threadIdx.x >> 4;
    const int bx = blockIdx.x, by = blockIdx.y, bz = blockIdx.z;
    const int ml = threadIdx.x >> 2;           // 0..63  (A row)
    const int kq = (threadIdx.x & 3) << 2;     // 0,4,8,12 (A k-quad)
    const int kb = threadIdx.x >> 4;           // 0..15  (B k)
    const int nb = (threadIdx.x & 15) << 2;    // 0..60  (B col quad)

    const float* Ap = feats + (size_t)(bx * 64 + ml) * SDIM + bz * 2048;
    const float* Bp = w1 + (size_t)(bz * 2048 + kb) * 256 + by * 64 + nb;

    float acc[4][4] = {{0.f}};
    for (int kt = 0; kt < 2048; kt += 16) {
        float4 av = *(const float4*)(Ap + kt + kq);
        float4 bv = *(const float4*)(Bp + (size_t)kt * 256);
        __syncthreads();
        As[kq + 0][ml] = av.x; As[kq + 1][ml] = av.y;
        As[kq + 2][ml] = av.z; As[kq + 3][ml] = av.w;
        *(float4*)&Bs[kb][nb] = bv;
        __syncthreads();
        #pragma unroll
        for (int k = 0; k < 16; ++k) {
            float4 a  = *(const float4*)&As[k][ty << 2];
            float4 b4 = *(const float4*)&Bs[k][tx << 2];
            acc[0][0] = fmaf(a.x, b4.x, acc[0][0]); acc[0][1] = fmaf(a.x, b4.y, acc[0][1]);
            acc[0][2] = fmaf(a.x, b4.z, acc[0][2]); acc[0][3] = fmaf(a.x, b4.w, acc[0][3]);
            acc[1][0] = fmaf(a.y, b4.x, acc[1][0]); acc[1][1] = fmaf(a.y, b4.y, acc[1][1]);
            acc[1][2] = fmaf(a.y, b4.z, acc[1][2]); acc[1][3] = fmaf(a.y, b4.w, acc[1][3]);
            acc[2][0] = fmaf(a.z, b4.x, acc[2][0]); acc[2][1] = fmaf(a.z, b4.y, acc[2][1]);
            acc[2][2] = fmaf(a.z, b4.z, acc[2][2]); acc[2][3] = fmaf(a.z, b4.w, acc[2][3]);
            acc[3][0] = fmaf(a.w, b4.x, acc[3][0]); acc[3][1] = fmaf(a.w, b4.y, acc[3][1]);
            acc[3][2] = fmaf(a.w, b4.z, acc[3][2]); acc[3][3] = fmaf(a.w, b4.w, acc[3][3]);
        }
    }
    float* Cp = part + ((size_t)bz * NBATCH + bx * 64 + (ty << 2)) * 256 + by * 64 + (tx << 2);
    #pragma unroll
    for (int i = 0; i < 4; ++i)
        *(float4*)(Cp + (size_t)i * 256) = make_float4(acc[i][0], acc[i][1], acc[i][2], acc[i][3]);
}

// ---------------------------------------------------------------------------
// Kernel 3: reduce split-K partials + bias + relu, then the two small GEMMs.
// ---------------------------------------------------------------------------
__global__ __launch_bounds__(256) void tail_kernel(
    const float* __restrict__ part,  // (8, 1024, 256)
    const float* __restrict__ b1,
    const float* __restrict__ w2,    // (256, 128)
    const float* __restrict__ b2,
    const float* __restrict__ w3,    // (128, 64)
    const float* __restrict__ b3,
    float* __restrict__ out)         // (1024, 64)
{
    __shared__ float h1[256];
    __shared__ float h2[128];
    const int b = blockIdx.x, t = threadIdx.x;

    float s = b1[t];
    #pragma unroll
    for (int sp = 0; sp < 8; ++sp)
        s += part[((size_t)sp * NBATCH + b) * 256 + t];
    h1[t] = fmaxf(s, 0.f);
    __syncthreads();

    if (t < 128) {
        float acc = b2[t];
        #pragma unroll 4
        for (int k = 0; k < 256; ++k) acc = fmaf(h1[k], w2[k * 128 + t], acc);
        h2[t] = fmaxf(acc, 0.f);
    }
    __syncthreads();

    if (t < 64) {
        float acc = b3[t];
        #pragma unroll 4
        for (int k = 0; k < 128; ++k) acc = fmaf(h2[k], w3[k * 64 + t], acc);
        out[(size_t)b * 64 + t] = acc;
    }
}

// ---------------------------------------------------------------------------
extern "C" void kernel_launch(void* const* d_in, const int* in_sizes, int n_in,
                              void* d_out, int out_size, void* d_ws, size_t ws_size,
                              hipStream_t stream) {
    const float* x   = (const float*)d_in[0];
    const float* ep  = (const float*)d_in[1];
    const float* rp  = (const float*)d_in[2];
    const float* ent = (const float*)d_in[3];
    const float* w1  = (const float*)d_in[4];
    const float* b1  = (const float*)d_in[5];
    const float* w2  = (const float*)d_in[6];
    const float* b2  = (const float*)d_in[7];
    const float* w3  = (const float*)d_in[8];
    const float* b3  = (const float*)d_in[9];
    float* out = (float*)d_out;

    // ws layout: feats (1024*16384 f32 = 64 MiB) | partials (8*1024*256 f32 = 8 MiB)
    float* feats = (float*)d_ws;
    float* part  = feats + (size_t)NBATCH * SDIM;

    const int SMEM = 131072 + (NGATES * 8 + 12) * (int)sizeof(float2) + 64;
    (void)hipFuncSetAttribute((const void*)sim_kernel,
                              hipFuncAttributeMaxDynamicSharedMemorySize, SMEM);

    sim_kernel<<<NBATCH, 1024, SMEM, stream>>>(x, ep, rp, ent, feats);
    gemm1_kernel<<<dim3(16, 4, 8), 256, 0, stream>>>(feats, w1, part);
    tail_kernel<<<NBATCH, 256, 0, stream>>>(part, b1, w2, b2, w3, b3, out);
}

// Round 7
// 399.389 us; speedup vs baseline: 1.1882x; 1.1882x over previous
//
#include <hip/hip_runtime.h>
#include <hip/hip_bf16.h>
#include <cstdint>
#include <cstddef>

#define NQ      14
#define SDIM    16384          // 1 << NQ
#define NGATES  39             // 3 layers * 13 sparse two-qubit chain gates
#define NBATCH  1024

// ---------------------------------------------------------------------------
// helpers
// ---------------------------------------------------------------------------
__device__ __forceinline__ float2 cmul(float2 a, float2 b) {
    return make_float2(fmaf(a.x, b.x, -a.y * b.y), fmaf(a.x, b.y, a.y * b.x));
}
__device__ __forceinline__ void cfma(float2 &o, float2 a, float2 b) {
    o.x = fmaf(a.x, b.x, fmaf(-a.y, b.y, o.x));
    o.y = fmaf(a.x, b.y, fmaf( a.y, b.x, o.y));
}

__device__ void mm2(const float2 A[2][2], const float2 B[2][2], float2 C[2][2]) {
    #pragma unroll
    for (int i = 0; i < 2; ++i)
        #pragma unroll
        for (int j = 0; j < 2; ++j) {
            float2 t = cmul(A[i][0], B[0][j]);
            cfma(t, A[i][1], B[1][j]);
            C[i][j] = t;
        }
}

// U = RZ(g) * RY(b) * RX(a)  (optionally right-multiplied by encoding RY for layer 0)
__device__ void build_u(const float* __restrict__ rp, const float* __restrict__ enc,
                        int l, int q, float2 U[2][2]) {
    const float* p = rp + (l * NQ + q) * 3;
    float ha = 0.5f * p[0], hb = 0.5f * p[1], hg = 0.5f * p[2];
    float cx = cosf(ha), sx = sinf(ha);
    float cy = cosf(hb), sy = sinf(hb);
    float cz = cosf(hg), sz = sinf(hg);
    float2 RX[2][2] = { { make_float2(cx, 0.f), make_float2(0.f, -sx) },
                        { make_float2(0.f, -sx), make_float2(cx, 0.f) } };
    float2 RY[2][2] = { { make_float2(cy, 0.f), make_float2(-sy, 0.f) },
                        { make_float2(sy, 0.f), make_float2(cy, 0.f) } };
    float2 W[2][2];
    mm2(RY, RX, W);
    float2 zl = make_float2(cz, -sz), zh = make_float2(cz, sz);
    float2 V[2][2];
    V[0][0] = cmul(zl, W[0][0]); V[0][1] = cmul(zl, W[0][1]);
    V[1][0] = cmul(zh, W[1][0]); V[1][1] = cmul(zh, W[1][1]);
    if (l == 0) {   // encoding RY applied BEFORE layer-0 rotations -> right-multiply
        float he = 0.5f * enc[q];
        float ce = cosf(he), se = sinf(he);
        float2 RE[2][2] = { { make_float2(ce, 0.f), make_float2(-se, 0.f) },
                            { make_float2(se, 0.f), make_float2(ce, 0.f) } };
        mm2(V, RE, U);
    } else {
        U[0][0] = V[0][0]; U[0][1] = V[0][1];
        U[1][0] = V[1][0]; U[1][1] = V[1][1];
    }
}

// ---------------------------------------------------------------------------
// Sparse chain-gate on the 4-qubit register window. Local basis bit CP = the
// gate's control qubit, CP+1 = target. 8 coeffs: [c0: m00,m01,m10,m11][c1: ...].
// ---------------------------------------------------------------------------
template<int CP>
__device__ __forceinline__ void gate_sparse8(float2 v[16], const float2* __restrict__ G) {
    {
        float2 c00 = G[0], c01 = G[1], c10 = G[2], c11 = G[3];
        #pragma unroll
        for (int rr = 0; rr < 4; ++rr) {
            const int base = ((rr >> CP) << (CP + 2)) | (rr & ((1 << CP) - 1));
            const int m0 = base, m2 = base | (2 << CP);
            float2 a0 = v[m0], a2 = v[m2];
            float2 o0 = cmul(c00, a0); cfma(o0, c01, a2);
            float2 o2 = cmul(c10, a0); cfma(o2, c11, a2);
            v[m0] = o0; v[m2] = o2;
        }
    }
    __builtin_amdgcn_sched_barrier(0);
    {
        float2 c00 = G[4], c01 = G[5], c10 = G[6], c11 = G[7];
        #pragma unroll
        for (int rr = 0; rr < 4; ++rr) {
            const int base = ((rr >> CP) << (CP + 2)) | (rr & ((1 << CP) - 1));
            const int m1 = base | (1 << CP), m3 = base | (3 << CP);
            float2 a1 = v[m1], a3 = v[m3];
            float2 o1 = cmul(c00, a1); cfma(o1, c01, a3);
            float2 o3 = cmul(c10, a1); cfma(o3, c11, a3);
            v[m1] = o1; v[m3] = o3;
        }
    }
}

// ---------------------------------------------------------------------------
// Per-pass amp-bit mappings. LDS layout: slot = amp ^ ((amp>>5)&31) — i.e.
// slot[4:0] = amp[4:0] ^ amp[9:5]; slot[13:5] = amp[13:5] unchanged.
// Window qubits W hold j (zero in i0); c_j = jW ^ ((jW>>5)&31) is compile-time
// => ONE live address register. Lane bits placed so every pass's b64 access
// covers all 16 bank-pairs x 4 lanes = conflict-free floor.
//   P0: W={0..3}   amp = l[3:0]<<5 | l4<<4 | l5<<9 | w<<10
//   P1: W={3..6}   amp = l[2:0]    | l3<<7 | ... (tid>>3 at amp 7..13)
//   P2: W={6..9}   amp = l4 | l[3:0]<<1 | l5<<5 | w<<10
//   P3: W={9..12}  amp = l1 | l3<<1 | l4<<2 | l5<<3 | l0<<4 | l2<<5 | w[2:0]<<6 | w3<<13
//   P4: W={10..13} amp = l[4:0] | w<<5 | l5<<9
// (l = lane bits tid[5:0], w = wave bits tid[9:6])
// ---------------------------------------------------------------------------
template<int P> __device__ __forceinline__ int pass_i0(int tid) {
    if constexpr (P == 0) return ((tid & 15) << 5) | (tid & 16) | ((tid & 32) << 4) | ((tid & 0x3C0) << 4);
    if constexpr (P == 1) return (tid & 7) | ((tid >> 3) << 7);
    if constexpr (P == 2) return ((tid >> 4) & 1) | ((tid & 15) << 1) | (((tid >> 5) & 1) << 5) | ((tid >> 6) << 10);
    if constexpr (P == 3) return ((tid >> 1) & 1) | (((tid >> 3) & 1) << 1) | (((tid >> 4) & 1) << 2)
                               | (((tid >> 5) & 1) << 3) | ((tid & 1) << 4) | (((tid >> 2) & 1) << 5)
                               | (((tid >> 6) & 7) << 6) | (((tid >> 9) & 1) << 13);
    if constexpr (P == 4) return (tid & 31) | (((tid >> 6) & 15) << 5) | (((tid >> 5) & 1) << 9);
    return 0;
}
// byte-offset XOR constant for window index j: c_j = (jW ^ ((jW>>5)&31)) * 8.
// FOLD APPLIES ONLY TO AMP BITS 5..9 (r6 bug: P3/P4 wrongly folded bits >=10).
template<int P> __device__ __forceinline__ constexpr int pass_cj(int j) {
    if constexpr (P == 0) return j * 8;                                   // W at amp 0..3: no fold source
    if constexpr (P == 1) return (((j << 3) | (j >> 2))) * 8;             // amp5,6 fold -> slot0,1
    if constexpr (P == 2) return (((j << 6) | (j << 1))) * 8;             // amp6..9 fold -> slot1..4
    if constexpr (P == 3) return (((j << 9) | ((j & 1) << 4))) * 8;       // only amp9 folds -> slot4
    if constexpr (P == 4) return (j << 10) * 8;                           // amp10..13: no fold
    return 0;
}

// One LDS round-trip: read 16 amps, apply this pass's gates, write back (or emit).
// P0: U0 + g(3k),g(3k+1),g(3k+2) at CP=0,1,2.  P1..P3: 3 gates.  P4: 1 gate at CP=2.
template<int P, bool INIT, bool U0F, bool EMIT>
__device__ __forceinline__ void passT(char* __restrict__ smemc,
                                      const float2* __restrict__ gb,
                                      const float2* __restrict__ u0,
                                      float* __restrict__ fr, int tid) {
    const int i0   = pass_i0<P>(tid);
    const int base = (i0 ^ ((i0 >> 5) & 31)) * 8;

    float2 v[16];
    if (INIT) {
        #pragma unroll
        for (int j = 0; j < 16; ++j) v[j] = make_float2(0.f, 0.f);
        if (tid == 0) v[0] = make_float2(1.f, 0.f);
    } else {
        #pragma unroll
        for (int j = 0; j < 16; ++j)
            v[j] = *(const float2*)(smemc + (base ^ pass_cj<P>(j)));
    }
    __builtin_amdgcn_sched_barrier(0);

    if (U0F) {   // 2x2 on local bit0 (qubit 0 is window bit 0 of pass P0)
        float2 u00 = u0[0], u01 = u0[1], u10 = u0[2], u11 = u0[3];
        #pragma unroll
        for (int k = 0; k < 8; ++k) {
            float2 e = v[2 * k], o = v[2 * k + 1];
            float2 ne = cmul(u00, e); cfma(ne, u01, o);
            float2 no = cmul(u10, e); cfma(no, u11, o);
            v[2 * k] = ne; v[2 * k + 1] = no;
        }
        __builtin_amdgcn_sched_barrier(0);
    }

    if (P < 4) {
        gate_sparse8<0>(v, gb);
        __builtin_amdgcn_sched_barrier(0);
        gate_sparse8<1>(v, gb + 8);
        __builtin_amdgcn_sched_barrier(0);
        gate_sparse8<2>(v, gb + 16);
        __builtin_amdgcn_sched_barrier(0);
    } else {
        gate_sparse8<2>(v, gb);
        __builtin_amdgcn_sched_barrier(0);
    }

    if (EMIT) {
        #pragma unroll
        for (int j = 0; j < 16; ++j)
            fr[i0 + (j << 10)] = fmaf(v[j].x, v[j].x, v[j].y * v[j].y);
    } else {
        int baseW = base;
        asm volatile("" : "+v"(baseW));   // anti-CSE: force fresh 1-reg address base
        #pragma unroll
        for (int j = 0; j < 16; ++j)
            *(float2*)(smemc + (baseW ^ pass_cj<P>(j))) = v[j];
    }
}

// ---------------------------------------------------------------------------
// Kernel 1: full circuit simulation, one workgroup per batch element.
// State in LDS (128 KiB, fold-XOR layout). 15 register-window passes
// (5/layer: {0-3}:g0-2+U0, {3-6}:g3-5, {6-9}:g6-8, {9-12}:g9-11, {10-13}:g12).
// ---------------------------------------------------------------------------
__global__ __launch_bounds__(1024) __attribute__((amdgpu_waves_per_eu(4, 4)))
void sim_kernel(
    const float* __restrict__ x,     // (1024, 64)
    const float* __restrict__ ep,    // (64, 14)
    const float* __restrict__ rp,    // (3, 14, 3)
    const float* __restrict__ ent,   // (3, 13)
    float* __restrict__ feats)       // (1024, 16384)
{
    extern __shared__ char smem[];
    char*   smemc = smem;                                            // 131072 B state
    float2* gmat  = (float2*)(smem + 131072);                        // 39*8*8 = 2496 B
    float2* u0m   = (float2*)(smem + 131072 + NGATES * 8 * (int)sizeof(float2));  // 96 B
    float*  angles = (float*)(smem + 131072 + (NGATES * 8 + 12) * (int)sizeof(float2));

    const int tid = threadIdx.x;
    const int b   = blockIdx.x;

    // --- encoding angles: one wave per qubit, shuffle-reduce ---
    if (tid < 14 * 64) {
        const int q = tid >> 6, k = tid & 63;
        float p = x[(size_t)b * 64 + k] * ep[k * NQ + q];
        #pragma unroll
        for (int off = 32; off; off >>= 1) p += __shfl_down(p, off, 64);
        if (k == 0) angles[q] = p;
    }
    __syncthreads();

    // --- build gate tables: 39 sparse chain gates + 3 per-layer U(q0) ---
    if (tid < NGATES) {
        int l = tid / 13, jj = tid - l * 13;     // gate on qubits (jj, jj+1)
        float2 Ut[2][2];
        build_u(rp, angles, l, jj + 1, Ut);
        float th = ent[l * 13 + jj];
        float ct = cosf(th), s = sinf(th);
        float2* G = gmat + tid * 8;
        // c=0 block: pcnot inactive -> Ut itself
        G[0] = Ut[0][0]; G[1] = Ut[0][1]; G[2] = Ut[1][0]; G[3] = Ut[1][1];
        // c=1 block: rows mixed by cos(th) + i sin(th) * X_target
        G[4] = make_float2(fmaf(ct, Ut[0][0].x, -s * Ut[1][0].y), fmaf(ct, Ut[0][0].y, s * Ut[1][0].x));
        G[5] = make_float2(fmaf(ct, Ut[0][1].x, -s * Ut[1][1].y), fmaf(ct, Ut[0][1].y, s * Ut[1][1].x));
        G[6] = make_float2(fmaf(ct, Ut[1][0].x, -s * Ut[0][0].y), fmaf(ct, Ut[1][0].y, s * Ut[0][0].x));
        G[7] = make_float2(fmaf(ct, Ut[1][1].x, -s * Ut[0][1].y), fmaf(ct, Ut[1][1].y, s * Ut[0][1].x));
    } else if (tid < NGATES + 3) {
        int l = tid - NGATES;
        float2 U[2][2];
        build_u(rp, angles, l, 0, U);
        float2* D = u0m + l * 4;
        D[0] = U[0][0]; D[1] = U[0][1]; D[2] = U[1][0]; D[3] = U[1][1];
    }
    __syncthreads();

    float* fr = feats + (size_t)b * SDIM;

    // --- layer 0 (synthesized from |0..0>, no initial LDS read) ---
    {
        const float2* gl = gmat;
        passT<0, true,  true,  false>(smemc, gl,          u0m,     nullptr, tid); __syncthreads();
        passT<1, false, false, false>(smemc, gl + 3 * 8,  nullptr, nullptr, tid); __syncthreads();
        passT<2, false, false, false>(smemc, gl + 6 * 8,  nullptr, nullptr, tid); __syncthreads();
        passT<3, false, false, false>(smemc, gl + 9 * 8,  nullptr, nullptr, tid); __syncthreads();
        passT<4, false, false, false>(smemc, gl + 12 * 8, nullptr, nullptr, tid); __syncthreads();
    }
    // --- layer 1 ---
    {
        const float2* gl = gmat + 13 * 8;
        passT<0, false, true,  false>(smemc, gl,          u0m + 4, nullptr, tid); __syncthreads();
        passT<1, false, false, false>(smemc, gl + 3 * 8,  nullptr, nullptr, tid); __syncthreads();
        passT<2, false, false, false>(smemc, gl + 6 * 8,  nullptr, nullptr, tid); __syncthreads();
        passT<3, false, false, false>(smemc, gl + 9 * 8,  nullptr, nullptr, tid); __syncthreads();
        passT<4, false, false, false>(smemc, gl + 12 * 8, nullptr, nullptr, tid); __syncthreads();
    }
    // --- layer 2 (final pass emits |amp|^2 straight to global, coalesced) ---
    {
        const float2* gl = gmat + 26 * 8;
        passT<0, false, true,  false>(smemc, gl,          u0m + 8, nullptr, tid); __syncthreads();
        passT<1, false, false, false>(smemc, gl + 3 * 8,  nullptr, nullptr, tid); __syncthreads();
        passT<2, false, false, false>(smemc, gl + 6 * 8,  nullptr, nullptr, tid); __syncthreads();
        passT<3, false, false, false>(smemc, gl + 9 * 8,  nullptr, nullptr, tid); __syncthreads();
        passT<4, false, false, true >(smemc, gl + 12 * 8, nullptr, fr,      tid);
    }
}

// ---------------------------------------------------------------------------
// Kernel 2: GEMM1 partials: part[bz] = feats[:, bz-chunk] @ w1[bz-chunk, :]
// M=1024, N=256, K=16384 split 8 ways. 64x64 tile, 4x4 per-thread regs.
// ---------------------------------------------------------------------------
__global__ __launch_bounds__(256) void gemm1_kernel(
    const float* __restrict__ feats,   // (1024, 16384)
    const float* __restrict__ w1,      // (16384, 256)
    float* __restrict__ part)          // (8, 1024, 256)
{
    __shared__ float As[16][68];
    __shared__ float Bs[16][68];
    const int tx = threadIdx.x & 15, ty = threadIdx.x >> 4;
    const int bx = blockIdx.x, by = blockIdx.y, bz = blockIdx.z;
    const int ml = threadIdx.x >> 2;           // 0..63  (A row)
    const int kq = (threadIdx.x & 3) << 2;     // 0,4,8,12 (A k-quad)
    const int kb = threadIdx.x >> 4;           // 0..15  (B k)
    const int nb = (threadIdx.x & 15) << 2;    // 0..60  (B col quad)

    const float* Ap = feats + (size_t)(bx * 64 + ml) * SDIM + bz * 2048;
    const float* Bp = w1 + (size_t)(bz * 2048 + kb) * 256 + by * 64 + nb;

    float acc[4][4] = {{0.f}};
    for (int kt = 0; kt < 2048; kt += 16) {
        float4 av = *(const float4*)(Ap + kt + kq);
        float4 bv = *(const float4*)(Bp + (size_t)kt * 256);
        __syncthreads();
        As[kq + 0][ml] = av.x; As[kq + 1][ml] = av.y;
        As[kq + 2][ml] = av.z; As[kq + 3][ml] = av.w;
        *(float4*)&Bs[kb][nb] = bv;
        __syncthreads();
        #pragma unroll
        for (int k = 0; k < 16; ++k) {
            float4 a  = *(const float4*)&As[k][ty << 2];
            float4 b4 = *(const float4*)&Bs[k][tx << 2];
            acc[0][0] = fmaf(a.x, b4.x, acc[0][0]); acc[0][1] = fmaf(a.x, b4.y, acc[0][1]);
            acc[0][2] = fmaf(a.x, b4.z, acc[0][2]); acc[0][3] = fmaf(a.x, b4.w, acc[0][3]);
            acc[1][0] = fmaf(a.y, b4.x, acc[1][0]); acc[1][1] = fmaf(a.y, b4.y, acc[1][1]);
            acc[1][2] = fmaf(a.y, b4.z, acc[1][2]); acc[1][3] = fmaf(a.y, b4.w, acc[1][3]);
            acc[2][0] = fmaf(a.z, b4.x, acc[2][0]); acc[2][1] = fmaf(a.z, b4.y, acc[2][1]);
            acc[2][2] = fmaf(a.z, b4.z, acc[2][2]); acc[2][3] = fmaf(a.z, b4.w, acc[2][3]);
            acc[3][0] = fmaf(a.w, b4.x, acc[3][0]); acc[3][1] = fmaf(a.w, b4.y, acc[3][1]);
            acc[3][2] = fmaf(a.w, b4.z, acc[3][2]); acc[3][3] = fmaf(a.w, b4.w, acc[3][3]);
        }
    }
    float* Cp = part + ((size_t)bz * NBATCH + bx * 64 + (ty << 2)) * 256 + by * 64 + (tx << 2);
    #pragma unroll
    for (int i = 0; i < 4; ++i)
        *(float4*)(Cp + (size_t)i * 256) = make_float4(acc[i][0], acc[i][1], acc[i][2], acc[i][3]);
}

// ---------------------------------------------------------------------------
// Kernel 3: reduce split-K partials + bias + relu, then the two small GEMMs.
// ---------------------------------------------------------------------------
__global__ __launch_bounds__(256) void tail_kernel(
    const float* __restrict__ part,  // (8, 1024, 256)
    const float* __restrict__ b1,
    const float* __restrict__ w2,    // (256, 128)
    const float* __restrict__ b2,
    const float* __restrict__ w3,    // (128, 64)
    const float* __restrict__ b3,
    float* __restrict__ out)         // (1024, 64)
{
    __shared__ float h1[256];
    __shared__ float h2[128];
    const int b = blockIdx.x, t = threadIdx.x;

    float s = b1[t];
    #pragma unroll
    for (int sp = 0; sp < 8; ++sp)
        s += part[((size_t)sp * NBATCH + b) * 256 + t];
    h1[t] = fmaxf(s, 0.f);
    __syncthreads();

    if (t < 128) {
        float acc = b2[t];
        #pragma unroll 4
        for (int k = 0; k < 256; ++k) acc = fmaf(h1[k], w2[k * 128 + t], acc);
        h2[t] = fmaxf(acc, 0.f);
    }
    __syncthreads();

    if (t < 64) {
        float acc = b3[t];
        #pragma unroll 4
        for (int k = 0; k < 128; ++k) acc = fmaf(h2[k], w3[k * 64 + t], acc);
        out[(size_t)b * 64 + t] = acc;
    }
}

// ---------------------------------------------------------------------------
extern "C" void kernel_launch(void* const* d_in, const int* in_sizes, int n_in,
                              void* d_out, int out_size, void* d_ws, size_t ws_size,
                              hipStream_t stream) {
    const float* x   = (const float*)d_in[0];
    const float* ep  = (const float*)d_in[1];
    const float* rp  = (const float*)d_in[2];
    const float* ent = (const float*)d_in[3];
    const float* w1  = (const float*)d_in[4];
    const float* b1  = (const float*)d_in[5];
    const float* w2  = (const float*)d_in[6];
    const float* b2  = (const float*)d_in[7];
    const float* w3  = (const float*)d_in[8];
    const float* b3  = (const float*)d_in[9];
    float* out = (float*)d_out;

    // ws layout: feats (1024*16384 f32 = 64 MiB) | partials (8*1024*256 f32 = 8 MiB)
    float* feats = (float*)d_ws;
    float* part  = feats + (size_t)NBATCH * SDIM;

    const int SMEM = 131072 + (NGATES * 8 + 12) * (int)sizeof(float2) + 64;
    (void)hipFuncSetAttribute((const void*)sim_kernel,
                              hipFuncAttributeMaxDynamicSharedMemorySize, SMEM);

    sim_kernel<<<NBATCH, 1024, SMEM, stream>>>(x, ep, rp, ent, feats);
    gemm1_kernel<<<dim3(16, 4, 8), 256, 0, stream>>>(feats, w1, part);
    tail_kernel<<<NBATCH, 256, 0, stream>>>(part, b1, w2, b2, w3, b3, out);
}

// Round 8
// 296.004 us; speedup vs baseline: 1.6032x; 1.3493x over previous
//
#include <hip/hip_runtime.h>
#include <hip/hip_bf16.h>
#include <cstdint>
#include <cstddef>

#define NQ      14
#define SDIM    16384          // 1 << NQ
#define NGATES  39             // 3 layers * 13 sparse two-qubit chain gates
#define NBATCH  1024

// ---------------------------------------------------------------------------
// helpers
// ---------------------------------------------------------------------------
__device__ __forceinline__ float2 cmul(float2 a, float2 b) {
    return make_float2(fmaf(a.x, b.x, -a.y * b.y), fmaf(a.x, b.y, a.y * b.x));
}
__device__ __forceinline__ void cfma(float2 &o, float2 a, float2 b) {
    o.x = fmaf(a.x, b.x, fmaf(-a.y, b.y, o.x));
    o.y = fmaf(a.x, b.y, fmaf( a.y, b.x, o.y));
}

__device__ void mm2(const float2 A[2][2], const float2 B[2][2], float2 C[2][2]) {
    #pragma unroll
    for (int i = 0; i < 2; ++i)
        #pragma unroll
        for (int j = 0; j < 2; ++j) {
            float2 t = cmul(A[i][0], B[0][j]);
            cfma(t, A[i][1], B[1][j]);
            C[i][j] = t;
        }
}

// U = RZ(g) * RY(b) * RX(a)  (optionally right-multiplied by encoding RY for layer 0)
__device__ void build_u(const float* __restrict__ rp, const float* __restrict__ enc,
                        int l, int q, float2 U[2][2]) {
    const float* p = rp + (l * NQ + q) * 3;
    float ha = 0.5f * p[0], hb = 0.5f * p[1], hg = 0.5f * p[2];
    float cx = cosf(ha), sx = sinf(ha);
    float cy = cosf(hb), sy = sinf(hb);
    float cz = cosf(hg), sz = sinf(hg);
    float2 RX[2][2] = { { make_float2(cx, 0.f), make_float2(0.f, -sx) },
                        { make_float2(0.f, -sx), make_float2(cx, 0.f) } };
    float2 RY[2][2] = { { make_float2(cy, 0.f), make_float2(-sy, 0.f) },
                        { make_float2(sy, 0.f), make_float2(cy, 0.f) } };
    float2 W[2][2];
    mm2(RY, RX, W);
    float2 zl = make_float2(cz, -sz), zh = make_float2(cz, sz);
    float2 V[2][2];
    V[0][0] = cmul(zl, W[0][0]); V[0][1] = cmul(zl, W[0][1]);
    V[1][0] = cmul(zh, W[1][0]); V[1][1] = cmul(zh, W[1][1]);
    if (l == 0) {   // encoding RY applied BEFORE layer-0 rotations -> right-multiply
        float he = 0.5f * enc[q];
        float ce = cosf(he), se = sinf(he);
        float2 RE[2][2] = { { make_float2(ce, 0.f), make_float2(-se, 0.f) },
                            { make_float2(se, 0.f), make_float2(ce, 0.f) } };
        mm2(V, RE, U);
    } else {
        U[0][0] = V[0][0]; U[0][1] = V[0][1];
        U[1][0] = V[1][0]; U[1][1] = V[1][1];
    }
}

// ---------------------------------------------------------------------------
// Sparse chain-gate on the 4-qubit register window. Local basis bit CP = the
// gate's control qubit, CP+1 = target. 8 coeffs: [c0: m00,m01,m10,m11][c1: ...].
// ---------------------------------------------------------------------------
template<int CP>
__device__ __forceinline__ void gate_sparse8(float2 v[16], const float2* __restrict__ G) {
    {
        float2 c00 = G[0], c01 = G[1], c10 = G[2], c11 = G[3];
        #pragma unroll
        for (int rr = 0; rr < 4; ++rr) {
            const int base = ((rr >> CP) << (CP + 2)) | (rr & ((1 << CP) - 1));
            const int m0 = base, m2 = base | (2 << CP);
            float2 a0 = v[m0], a2 = v[m2];
            float2 o0 = cmul(c00, a0); cfma(o0, c01, a2);
            float2 o2 = cmul(c10, a0); cfma(o2, c11, a2);
            v[m0] = o0; v[m2] = o2;
        }
    }
    {
        float2 c00 = G[4], c01 = G[5], c10 = G[6], c11 = G[7];
        #pragma unroll
        for (int rr = 0; rr < 4; ++rr) {
            const int base = ((rr >> CP) << (CP + 2)) | (rr & ((1 << CP) - 1));
            const int m1 = base | (1 << CP), m3 = base | (3 << CP);
            float2 a1 = v[m1], a3 = v[m3];
            float2 o1 = cmul(c00, a1); cfma(o1, c01, a3);
            float2 o3 = cmul(c10, a1); cfma(o3, c11, a3);
            v[m1] = o1; v[m3] = o3;
        }
    }
}

// ---------------------------------------------------------------------------
// LDS layout: slot = amp ^ ((amp>>5)&31)  (slot[4:0] = amp[4:0]^amp[9:5]).
// Bank-pair of an 8B access = slot[3:0]. b64 conflict-freedom on gfx950 needs
// each 16-LANE GROUP to cover all 16 bank-pairs (r7 lesson: P1/P2/P3 violated
// this -> 1.9e7 conflict cycles). All five mappings below give
// slot[3:0] = bijection(l[3:0]) ^ group-consts, and window bits W hold zero in
// i0 so slot(j) = slot0 ^ c_j with c_j compile-time (ONE address register).
//   P0: W={0..3}   amp = l[3:0]<<5 | l4<<4 | l5<<9 | w<<10
//   P1: W={3..6}   amp = l[2:0] | l4<<7 | l3<<8 | l5<<9 | w<<10
//   P2: W={6..9}   amp = l[3:0] | l4<<4 | l5<<5 | w<<10
//   P3: W={9..12}  amp = l[3:0] | w3<<4 | l4<<5 | l5<<6 | w0<<7 | w1<<8 | w2<<13
//   P4: W={10..13} amp = l[4:0] | w<<5 | l5<<9
// (l = tid[5:0] lane bits, w = tid[9:6] wave bits)
// ---------------------------------------------------------------------------
template<int P> __device__ __forceinline__ int pass_i0(int tid) {
    if constexpr (P == 0) return ((tid & 15) << 5) | (tid & 16) | ((tid & 32) << 4) | ((tid & 0x3C0) << 4);
    if constexpr (P == 1) return (tid & 7) | (((tid >> 4) & 1) << 7) | (((tid >> 3) & 1) << 8)
                               | (((tid >> 5) & 1) << 9) | ((tid >> 6) << 10);
    if constexpr (P == 2) return (tid & 63) | ((tid >> 6) << 10);
    if constexpr (P == 3) return (tid & 15) | (((tid >> 9) & 1) << 4) | (((tid >> 4) & 1) << 5)
                               | (((tid >> 5) & 1) << 6) | (((tid >> 6) & 1) << 7)
                               | (((tid >> 7) & 1) << 8) | (((tid >> 8) & 1) << 13);
    if constexpr (P == 4) return (tid & 31) | (((tid >> 6) & 15) << 5) | (((tid >> 5) & 1) << 9);
    return 0;
}
// byte-offset XOR constant for window index j: c_j = (fold(j << Wbase)) * 8.
// Fold source is amp[9:5] only.
template<int P> __device__ __forceinline__ constexpr int pass_cj(int j) {
    if constexpr (P == 0) return j * 8;                              // W amp0..3: no fold
    if constexpr (P == 1) return (((j << 3) | (j >> 2))) * 8;        // amp5,6 fold -> slot0,1
    if constexpr (P == 2) return (((j << 6) | (j << 1))) * 8;        // amp6..9 fold -> slot1..4
    if constexpr (P == 3) return (((j << 9) | ((j & 1) << 4))) * 8;  // only amp9 folds -> slot4
    if constexpr (P == 4) return (j << 10) * 8;                      // amp10..13: no fold
    return 0;
}

// One LDS round-trip: read 16 amps, apply this pass's gates, write back (or emit).
// P0: U0 + gates CP=0,1,2.  P1..P3: 3 gates.  P4: 1 gate at CP=2.
template<int P, bool INIT, bool U0F, bool EMIT>
__device__ __forceinline__ void passT(char* __restrict__ smemc,
                                      const float2* __restrict__ gb,
                                      const float2* __restrict__ u0,
                                      float* __restrict__ fr, int tid) {
    const int i0   = pass_i0<P>(tid);
    const int base = (i0 ^ ((i0 >> 5) & 31)) * 8;

    float2 v[16];
    if (INIT) {
        #pragma unroll
        for (int j = 0; j < 16; ++j) v[j] = make_float2(0.f, 0.f);
        if (tid == 0) v[0] = make_float2(1.f, 0.f);
    } else {
        #pragma unroll
        for (int j = 0; j < 16; ++j)
            v[j] = *(const float2*)(smemc + (base ^ pass_cj<P>(j)));
    }

    if (U0F) {   // 2x2 on local bit0 (qubit 0 = window bit 0 of pass P0)
        float2 u00 = u0[0], u01 = u0[1], u10 = u0[2], u11 = u0[3];
        #pragma unroll
        for (int k = 0; k < 8; ++k) {
            float2 e = v[2 * k], o = v[2 * k + 1];
            float2 ne = cmul(u00, e); cfma(ne, u01, o);
            float2 no = cmul(u10, e); cfma(no, u11, o);
            v[2 * k] = ne; v[2 * k + 1] = no;
        }
    }

    if (P < 4) {
        gate_sparse8<0>(v, gb);
        gate_sparse8<1>(v, gb + 8);
        gate_sparse8<2>(v, gb + 16);
    } else {
        gate_sparse8<2>(v, gb);
    }

    if (EMIT) {
        #pragma unroll
        for (int j = 0; j < 16; ++j)
            fr[i0 + (j << 10)] = fmaf(v[j].x, v[j].x, v[j].y * v[j].y);
    } else {
        #pragma unroll
        for (int j = 0; j < 16; ++j)
            *(float2*)(smemc + (base ^ pass_cj<P>(j))) = v[j];
    }
}

// ---------------------------------------------------------------------------
// Kernel 1: full circuit simulation, one workgroup per batch element.
// STATIC __shared__ (133.7 KB < 160 KB gfx950): makes the 1-block/CU occupancy
// visible to the register allocator (dynamic LDS kept it targeting 8 waves/EU
// => 64-VGPR cap => ~370 MB/dispatch scratch spill in r2-r7).
// ---------------------------------------------------------------------------
__global__ __launch_bounds__(1024) __attribute__((amdgpu_waves_per_eu(4, 4)))
void sim_kernel(
    const float* __restrict__ x,     // (1024, 64)
    const float* __restrict__ ep,    // (64, 14)
    const float* __restrict__ rp,    // (3, 14, 3)
    const float* __restrict__ ent,   // (3, 13)
    float* __restrict__ feats)       // (1024, 16384)
{
    __shared__ float2 st[SDIM];            // 131072 B
    __shared__ float2 gmat[NGATES * 8];    // 2496 B
    __shared__ float2 u0m[12];             // 96 B
    __shared__ float  angles[NQ];          // 56 B

    char* smemc = (char*)st;
    const int tid = threadIdx.x;
    const int b   = blockIdx.x;

    // --- encoding angles: one wave per qubit, shuffle-reduce ---
    if (tid < 14 * 64) {
        const int q = tid >> 6, k = tid & 63;
        float p = x[(size_t)b * 64 + k] * ep[k * NQ + q];
        #pragma unroll
        for (int off = 32; off; off >>= 1) p += __shfl_down(p, off, 64);
        if (k == 0) angles[q] = p;
    }
    __syncthreads();

    // --- build gate tables: 39 sparse chain gates + 3 per-layer U(q0) ---
    if (tid < NGATES) {
        int l = tid / 13, jj = tid - l * 13;     // gate on qubits (jj, jj+1)
        float2 Ut[2][2];
        build_u(rp, angles, l, jj + 1, Ut);
        float th = ent[l * 13 + jj];
        float ct = cosf(th), s = sinf(th);
        float2* G = gmat + tid * 8;
        // c=0 block: pcnot inactive -> Ut itself
        G[0] = Ut[0][0]; G[1] = Ut[0][1]; G[2] = Ut[1][0]; G[3] = Ut[1][1];
        // c=1 block: rows mixed by cos(th) + i sin(th) * X_target
        G[4] = make_float2(fmaf(ct, Ut[0][0].x, -s * Ut[1][0].y), fmaf(ct, Ut[0][0].y, s * Ut[1][0].x));
        G[5] = make_float2(fmaf(ct, Ut[0][1].x, -s * Ut[1][1].y), fmaf(ct, Ut[0][1].y, s * Ut[1][1].x));
        G[6] = make_float2(fmaf(ct, Ut[1][0].x, -s * Ut[0][0].y), fmaf(ct, Ut[1][0].y, s * Ut[0][0].x));
        G[7] = make_float2(fmaf(ct, Ut[1][1].x, -s * Ut[0][1].y), fmaf(ct, Ut[1][1].y, s * Ut[0][1].x));
    } else if (tid < NGATES + 3) {
        int l = tid - NGATES;
        float2 U[2][2];
        build_u(rp, angles, l, 0, U);
        float2* D = u0m + l * 4;
        D[0] = U[0][0]; D[1] = U[0][1]; D[2] = U[1][0]; D[3] = U[1][1];
    }
    __syncthreads();

    float* fr = feats + (size_t)b * SDIM;

    // --- layer 0 (synthesized from |0..0>, no initial LDS read) ---
    {
        const float2* gl = gmat;
        passT<0, true,  true,  false>(smemc, gl,          u0m,     nullptr, tid); __syncthreads();
        passT<1, false, false, false>(smemc, gl + 3 * 8,  nullptr, nullptr, tid); __syncthreads();
        passT<2, false, false, false>(smemc, gl + 6 * 8,  nullptr, nullptr, tid); __syncthreads();
        passT<3, false, false, false>(smemc, gl + 9 * 8,  nullptr, nullptr, tid); __syncthreads();
        passT<4, false, false, false>(smemc, gl + 12 * 8, nullptr, nullptr, tid); __syncthreads();
    }
    // --- layer 1 ---
    {
        const float2* gl = gmat + 13 * 8;
        passT<0, false, true,  false>(smemc, gl,          u0m + 4, nullptr, tid); __syncthreads();
        passT<1, false, false, false>(smemc, gl + 3 * 8,  nullptr, nullptr, tid); __syncthreads();
        passT<2, false, false, false>(smemc, gl + 6 * 8,  nullptr, nullptr, tid); __syncthreads();
        passT<3, false, false, false>(smemc, gl + 9 * 8,  nullptr, nullptr, tid); __syncthreads();
        passT<4, false, false, false>(smemc, gl + 12 * 8, nullptr, nullptr, tid); __syncthreads();
    }
    // --- layer 2 (final pass emits |amp|^2 straight to global, coalesced) ---
    {
        const float2* gl = gmat + 26 * 8;
        passT<0, false, true,  false>(smemc, gl,          u0m + 8, nullptr, tid); __syncthreads();
        passT<1, false, false, false>(smemc, gl + 3 * 8,  nullptr, nullptr, tid); __syncthreads();
        passT<2, false, false, false>(smemc, gl + 6 * 8,  nullptr, nullptr, tid); __syncthreads();
        passT<3, false, false, false>(smemc, gl + 9 * 8,  nullptr, nullptr, tid); __syncthreads();
        passT<4, false, false, true >(smemc, gl + 12 * 8, nullptr, fr,      tid);
    }
}

// ---------------------------------------------------------------------------
// Kernel 2: GEMM1 partials: part[bz] = feats[:, bz-chunk] @ w1[bz-chunk, :]
// M=1024, N=256, K=16384 split 8 ways. 64x64 tile, 4x4 per-thread regs.
// ---------------------------------------------------------------------------
__global__ __launch_bounds__(256) void gemm1_kernel(
    const float* __restrict__ feats,   // (1024, 16384)
    const float* __restrict__ w1,      // (16384, 256)
    float* __restrict__ part)          // (8, 1024, 256)
{
    __shared__ float As[16][68];
    __shared__ float Bs[16][68];
    const int tx = threadIdx.x & 15, ty = threadIdx.x >> 4;
    const int bx = blockIdx.x, by = blockIdx.y, bz = blockIdx.z;
    const int ml = threadIdx.x >> 2;           // 0..63  (A row)
    const int kq = (threadIdx.x & 3) << 2;     // 0,4,8,12 (A k-quad)
    const int kb = threadIdx.x >> 4;           // 0..15  (B k)
    const int nb = (threadIdx.x & 15) << 2;    // 0..60  (B col quad)

    const float* Ap = feats + (size_t)(bx * 64 + ml) * SDIM + bz * 2048;
    const float* Bp = w1 + (size_t)(bz * 2048 + kb) * 256 + by * 64 + nb;

    float acc[4][4] = {{0.f}};
    for (int kt = 0; kt < 2048; kt += 16) {
        float4 av = *(const float4*)(Ap + kt + kq);
        float4 bv = *(const float4*)(Bp + (size_t)kt * 256);
        __syncthreads();
        As[kq + 0][ml] = av.x; As[kq + 1][ml] = av.y;
        As[kq + 2][ml] = av.z; As[kq + 3][ml] = av.w;
        *(float4*)&Bs[kb][nb] = bv;
        __syncthreads();
        #pragma unroll
        for (int k = 0; k < 16; ++k) {
            float4 a  = *(const float4*)&As[k][ty << 2];
            float4 b4 = *(const float4*)&Bs[k][tx << 2];
            acc[0][0] = fmaf(a.x, b4.x, acc[0][0]); acc[0][1] = fmaf(a.x, b4.y, acc[0][1]);
            acc[0][2] = fmaf(a.x, b4.z, acc[0][2]); acc[0][3] = fmaf(a.x, b4.w, acc[0][3]);
            acc[1][0] = fmaf(a.y, b4.x, acc[1][0]); acc[1][1] = fmaf(a.y, b4.y, acc[1][1]);
            acc[1][2] = fmaf(a.y, b4.z, acc[1][2]); acc[1][3] = fmaf(a.y, b4.w, acc[1][3]);
            acc[2][0] = fmaf(a.z, b4.x, acc[2][0]); acc[2][1] = fmaf(a.z, b4.y, acc[2][1]);
            acc[2][2] = fmaf(a.z, b4.z, acc[2][2]); acc[2][3] = fmaf(a.z, b4.w, acc[2][3]);
            acc[3][0] = fmaf(a.w, b4.x, acc[3][0]); acc[3][1] = fmaf(a.w, b4.y, acc[3][1]);
            acc[3][2] = fmaf(a.w, b4.z, acc[3][2]); acc[3][3] = fmaf(a.w, b4.w, acc[3][3]);
        }
    }
    float* Cp = part + ((size_t)bz * NBATCH + bx * 64 + (ty << 2)) * 256 + by * 64 + (tx << 2);
    #pragma unroll
    for (int i = 0; i < 4; ++i)
        *(float4*)(Cp + (size_t)i * 256) = make_float4(acc[i][0], acc[i][1], acc[i][2], acc[i][3]);
}

// ---------------------------------------------------------------------------
// Kernel 3: reduce split-K partials + bias + relu, then the two small GEMMs.
// ---------------------------------------------------------------------------
__global__ __launch_bounds__(256) void tail_kernel(
    const float* __restrict__ part,  // (8, 1024, 256)
    const float* __restrict__ b1,
    const float* __restrict__ w2,    // (256, 128)
    const float* __restrict__ b2,
    const float* __restrict__ w3,    // (128, 64)
    const float* __restrict__ b3,
    float* __restrict__ out)         // (1024, 64)
{
    __shared__ float h1[256];
    __shared__ float h2[128];
    const int b = blockIdx.x, t = threadIdx.x;

    float s = b1[t];
    #pragma unroll
    for (int sp = 0; sp < 8; ++sp)
        s += part[((size_t)sp * NBATCH + b) * 256 + t];
    h1[t] = fmaxf(s, 0.f);
    __syncthreads();

    if (t < 128) {
        float acc = b2[t];
        #pragma unroll 4
        for (int k = 0; k < 256; ++k) acc = fmaf(h1[k], w2[k * 128 + t], acc);
        h2[t] = fmaxf(acc, 0.f);
    }
    __syncthreads();

    if (t < 64) {
        float acc = b3[t];
        #pragma unroll 4
        for (int k = 0; k < 128; ++k) acc = fmaf(h2[k], w3[k * 64 + t], acc);
        out[(size_t)b * 64 + t] = acc;
    }
}

// ---------------------------------------------------------------------------
extern "C" void kernel_launch(void* const* d_in, const int* in_sizes, int n_in,
                              void* d_out, int out_size, void* d_ws, size_t ws_size,
                              hipStream_t stream) {
    const float* x   = (const float*)d_in[0];
    const float* ep  = (const float*)d_in[1];
    const float* rp  = (const float*)d_in[2];
    const float* ent = (const float*)d_in[3];
    const float* w1  = (const float*)d_in[4];
    const float* b1  = (const float*)d_in[5];
    const float* w2  = (const float*)d_in[6];
    const float* b2  = (const float*)d_in[7];
    const float* w3  = (const float*)d_in[8];
    const float* b3  = (const float*)d_in[9];
    float* out = (float*)d_out;

    // ws layout: feats (1024*16384 f32 = 64 MiB) | partials (8*1024*256 f32 = 8 MiB)
    float* feats = (float*)d_ws;
    float* part  = feats + (size_t)NBATCH * SDIM;

    sim_kernel<<<NBATCH, 1024, 0, stream>>>(x, ep, rp, ent, feats);
    gemm1_kernel<<<dim3(16, 4, 8), 256, 0, stream>>>(feats, w1, part);
    tail_kernel<<<NBATCH, 256, 0, stream>>>(part, b1, w2, b2, w3, b3, out);
}

// Round 9
// 194.492 us; speedup vs baseline: 2.4400x; 1.5219x over previous
//
#include <hip/hip_runtime.h>
#include <hip/hip_bf16.h>
#include <cstdint>
#include <cstddef>

#define NQ      14
#define SDIM    16384          // 1 << NQ
#define NGATES  39             // 3 layers * 13 sparse two-qubit chain gates
#define NBATCH  1024
#define KSPLIT  16

typedef short bf16x8 __attribute__((ext_vector_type(8)));
typedef float f32x4  __attribute__((ext_vector_type(4)));

// ---------------------------------------------------------------------------
// helpers
// ---------------------------------------------------------------------------
__device__ __forceinline__ float2 cmul(float2 a, float2 b) {
    return make_float2(fmaf(a.x, b.x, -a.y * b.y), fmaf(a.x, b.y, a.y * b.x));
}
__device__ __forceinline__ void cfma(float2 &o, float2 a, float2 b) {
    o.x = fmaf(a.x, b.x, fmaf(-a.y, b.y, o.x));
    o.y = fmaf(a.x, b.y, fmaf( a.y, b.x, o.y));
}

__device__ void mm2(const float2 A[2][2], const float2 B[2][2], float2 C[2][2]) {
    #pragma unroll
    for (int i = 0; i < 2; ++i)
        #pragma unroll
        for (int j = 0; j < 2; ++j) {
            float2 t = cmul(A[i][0], B[0][j]);
            cfma(t, A[i][1], B[1][j]);
            C[i][j] = t;
        }
}

// U = RZ(g) * RY(b) * RX(a)  (optionally right-multiplied by encoding RY for layer 0)
__device__ void build_u(const float* __restrict__ rp, const float* __restrict__ enc,
                        int l, int q, float2 U[2][2]) {
    const float* p = rp + (l * NQ + q) * 3;
    float ha = 0.5f * p[0], hb = 0.5f * p[1], hg = 0.5f * p[2];
    float cx = cosf(ha), sx = sinf(ha);
    float cy = cosf(hb), sy = sinf(hb);
    float cz = cosf(hg), sz = sinf(hg);
    float2 RX[2][2] = { { make_float2(cx, 0.f), make_float2(0.f, -sx) },
                        { make_float2(0.f, -sx), make_float2(cx, 0.f) } };
    float2 RY[2][2] = { { make_float2(cy, 0.f), make_float2(-sy, 0.f) },
                        { make_float2(sy, 0.f), make_float2(cy, 0.f) } };
    float2 W[2][2];
    mm2(RY, RX, W);
    float2 zl = make_float2(cz, -sz), zh = make_float2(cz, sz);
    float2 V[2][2];
    V[0][0] = cmul(zl, W[0][0]); V[0][1] = cmul(zl, W[0][1]);
    V[1][0] = cmul(zh, W[1][0]); V[1][1] = cmul(zh, W[1][1]);
    if (l == 0) {   // encoding RY applied BEFORE layer-0 rotations -> right-multiply
        float he = 0.5f * enc[q];
        float ce = cosf(he), se = sinf(he);
        float2 RE[2][2] = { { make_float2(ce, 0.f), make_float2(-se, 0.f) },
                            { make_float2(se, 0.f), make_float2(ce, 0.f) } };
        mm2(V, RE, U);
    } else {
        U[0][0] = V[0][0]; U[0][1] = V[0][1];
        U[1][0] = V[1][0]; U[1][1] = V[1][1];
    }
}

// ---------------------------------------------------------------------------
// Sparse chain-gate on the 4-qubit register window (unchanged from r8).
// ---------------------------------------------------------------------------
template<int CP>
__device__ __forceinline__ void gate_sparse8(float2 v[16], const float2* __restrict__ G) {
    {
        float2 c00 = G[0], c01 = G[1], c10 = G[2], c11 = G[3];
        #pragma unroll
        for (int rr = 0; rr < 4; ++rr) {
            const int base = ((rr >> CP) << (CP + 2)) | (rr & ((1 << CP) - 1));
            const int m0 = base, m2 = base | (2 << CP);
            float2 a0 = v[m0], a2 = v[m2];
            float2 o0 = cmul(c00, a0); cfma(o0, c01, a2);
            float2 o2 = cmul(c10, a0); cfma(o2, c11, a2);
            v[m0] = o0; v[m2] = o2;
        }
    }
    {
        float2 c00 = G[4], c01 = G[5], c10 = G[6], c11 = G[7];
        #pragma unroll
        for (int rr = 0; rr < 4; ++rr) {
            const int base = ((rr >> CP) << (CP + 2)) | (rr & ((1 << CP) - 1));
            const int m1 = base | (1 << CP), m3 = base | (3 << CP);
            float2 a1 = v[m1], a3 = v[m3];
            float2 o1 = cmul(c00, a1); cfma(o1, c01, a3);
            float2 o3 = cmul(c10, a1); cfma(o3, c11, a3);
            v[m1] = o1; v[m3] = o3;
        }
    }
}

// Per-pass amp-bit mappings (unchanged from r8 — passed + low conflicts).
template<int P> __device__ __forceinline__ int pass_i0(int tid) {
    if constexpr (P == 0) return ((tid & 15) << 5) | (tid & 16) | ((tid & 32) << 4) | ((tid & 0x3C0) << 4);
    if constexpr (P == 1) return (tid & 7) | (((tid >> 4) & 1) << 7) | (((tid >> 3) & 1) << 8)
                               | (((tid >> 5) & 1) << 9) | ((tid >> 6) << 10);
    if constexpr (P == 2) return (tid & 63) | ((tid >> 6) << 10);
    if constexpr (P == 3) return (tid & 15) | (((tid >> 9) & 1) << 4) | (((tid >> 4) & 1) << 5)
                               | (((tid >> 5) & 1) << 6) | (((tid >> 6) & 1) << 7)
                               | (((tid >> 7) & 1) << 8) | (((tid >> 8) & 1) << 13);
    if constexpr (P == 4) return (tid & 31) | (((tid >> 6) & 15) << 5) | (((tid >> 5) & 1) << 9);
    return 0;
}
template<int P> __device__ __forceinline__ constexpr int pass_cj(int j) {
    if constexpr (P == 0) return j * 8;
    if constexpr (P == 1) return (((j << 3) | (j >> 2))) * 8;
    if constexpr (P == 2) return (((j << 6) | (j << 1))) * 8;
    if constexpr (P == 3) return (((j << 9) | ((j & 1) << 4))) * 8;
    if constexpr (P == 4) return (j << 10) * 8;
    return 0;
}

template<int P, bool INIT, bool U0F, bool EMIT>
__device__ __forceinline__ void passT(char* __restrict__ smemc,
                                      const float2* __restrict__ gb,
                                      const float2* __restrict__ u0,
                                      __hip_bfloat16* __restrict__ fr, int tid) {
    const int i0   = pass_i0<P>(tid);
    const int base = (i0 ^ ((i0 >> 5) & 31)) * 8;

    float2 v[16];
    if (INIT) {
        #pragma unroll
        for (int j = 0; j < 16; ++j) v[j] = make_float2(0.f, 0.f);
        if (tid == 0) v[0] = make_float2(1.f, 0.f);
    } else {
        #pragma unroll
        for (int j = 0; j < 16; ++j)
            v[j] = *(const float2*)(smemc + (base ^ pass_cj<P>(j)));
    }

    if (U0F) {
        float2 u00 = u0[0], u01 = u0[1], u10 = u0[2], u11 = u0[3];
        #pragma unroll
        for (int k = 0; k < 8; ++k) {
            float2 e = v[2 * k], o = v[2 * k + 1];
            float2 ne = cmul(u00, e); cfma(ne, u01, o);
            float2 no = cmul(u10, e); cfma(no, u11, o);
            v[2 * k] = ne; v[2 * k + 1] = no;
        }
    }

    if (P < 4) {
        gate_sparse8<0>(v, gb);
        gate_sparse8<1>(v, gb + 8);
        gate_sparse8<2>(v, gb + 16);
    } else {
        gate_sparse8<2>(v, gb);
    }

    if (EMIT) {
        #pragma unroll
        for (int j = 0; j < 16; ++j)
            fr[i0 + (j << 10)] = __float2bfloat16(fmaf(v[j].x, v[j].x, v[j].y * v[j].y));
    } else {
        #pragma unroll
        for (int j = 0; j < 16; ++j)
            *(float2*)(smemc + (base ^ pass_cj<P>(j))) = v[j];
    }
}

// ---------------------------------------------------------------------------
// Kernel 1: circuit simulation (static LDS — r8: kills the spill). Emits
// feats directly as bf16 (MFMA consumer; halves write traffic).
// ---------------------------------------------------------------------------
__global__ __launch_bounds__(1024) __attribute__((amdgpu_waves_per_eu(4, 4)))
void sim_kernel(
    const float* __restrict__ x,     // (1024, 64)
    const float* __restrict__ ep,    // (64, 14)
    const float* __restrict__ rp,    // (3, 14, 3)
    const float* __restrict__ ent,   // (3, 13)
    __hip_bfloat16* __restrict__ feats)  // (1024, 16384) bf16
{
    __shared__ float2 st[SDIM];            // 131072 B
    __shared__ float2 gmat[NGATES * 8];    // 2496 B
    __shared__ float2 u0m[12];             // 96 B
    __shared__ float  angles[NQ];          // 56 B

    char* smemc = (char*)st;
    const int tid = threadIdx.x;
    const int b   = blockIdx.x;

    if (tid < 14 * 64) {
        const int q = tid >> 6, k = tid & 63;
        float p = x[(size_t)b * 64 + k] * ep[k * NQ + q];
        #pragma unroll
        for (int off = 32; off; off >>= 1) p += __shfl_down(p, off, 64);
        if (k == 0) angles[q] = p;
    }
    __syncthreads();

    if (tid < NGATES) {
        int l = tid / 13, jj = tid - l * 13;
        float2 Ut[2][2];
        build_u(rp, angles, l, jj + 1, Ut);
        float th = ent[l * 13 + jj];
        float ct = cosf(th), s = sinf(th);
        float2* G = gmat + tid * 8;
        G[0] = Ut[0][0]; G[1] = Ut[0][1]; G[2] = Ut[1][0]; G[3] = Ut[1][1];
        G[4] = make_float2(fmaf(ct, Ut[0][0].x, -s * Ut[1][0].y), fmaf(ct, Ut[0][0].y, s * Ut[1][0].x));
        G[5] = make_float2(fmaf(ct, Ut[0][1].x, -s * Ut[1][1].y), fmaf(ct, Ut[0][1].y, s * Ut[1][1].x));
        G[6] = make_float2(fmaf(ct, Ut[1][0].x, -s * Ut[0][0].y), fmaf(ct, Ut[1][0].y, s * Ut[0][0].x));
        G[7] = make_float2(fmaf(ct, Ut[1][1].x, -s * Ut[0][1].y), fmaf(ct, Ut[1][1].y, s * Ut[0][1].x));
    } else if (tid < NGATES + 3) {
        int l = tid - NGATES;
        float2 U[2][2];
        build_u(rp, angles, l, 0, U);
        float2* D = u0m + l * 4;
        D[0] = U[0][0]; D[1] = U[0][1]; D[2] = U[1][0]; D[3] = U[1][1];
    }
    __syncthreads();

    __hip_bfloat16* fr = feats + (size_t)b * SDIM;

    {
        const float2* gl = gmat;
        passT<0, true,  true,  false>(smemc, gl,          u0m,     nullptr, tid); __syncthreads();
        passT<1, false, false, false>(smemc, gl + 3 * 8,  nullptr, nullptr, tid); __syncthreads();
        passT<2, false, false, false>(smemc, gl + 6 * 8,  nullptr, nullptr, tid); __syncthreads();
        passT<3, false, false, false>(smemc, gl + 9 * 8,  nullptr, nullptr, tid); __syncthreads();
        passT<4, false, false, false>(smemc, gl + 12 * 8, nullptr, nullptr, tid); __syncthreads();
    }
    {
        const float2* gl = gmat + 13 * 8;
        passT<0, false, true,  false>(smemc, gl,          u0m + 4, nullptr, tid); __syncthreads();
        passT<1, false, false, false>(smemc, gl + 3 * 8,  nullptr, nullptr, tid); __syncthreads();
        passT<2, false, false, false>(smemc, gl + 6 * 8,  nullptr, nullptr, tid); __syncthreads();
        passT<3, false, false, false>(smemc, gl + 9 * 8,  nullptr, nullptr, tid); __syncthreads();
        passT<4, false, false, false>(smemc, gl + 12 * 8, nullptr, nullptr, tid); __syncthreads();
    }
    {
        const float2* gl = gmat + 26 * 8;
        passT<0, false, true,  false>(smemc, gl,          u0m + 8, nullptr, tid); __syncthreads();
        passT<1, false, false, false>(smemc, gl + 3 * 8,  nullptr, nullptr, tid); __syncthreads();
        passT<2, false, false, false>(smemc, gl + 6 * 8,  nullptr, nullptr, tid); __syncthreads();
        passT<3, false, false, false>(smemc, gl + 9 * 8,  nullptr, nullptr, tid); __syncthreads();
        passT<4, false, false, true >(smemc, gl + 12 * 8, nullptr, fr,      tid);
    }
}

// ---------------------------------------------------------------------------
// Kernel 1b: w1 (16384,256) fp32 -> w1t (256,16384) bf16 (transpose+convert).
// Both MFMA operands need k-contiguous storage.
// ---------------------------------------------------------------------------
__global__ __launch_bounds__(256) void wtr_kernel(
    const float* __restrict__ w1, __hip_bfloat16* __restrict__ w1t)
{
    __shared__ float tile[64][65];
    const int kb = blockIdx.x * 64, nb = blockIdx.y * 64;
    const int t = threadIdx.x;
    #pragma unroll
    for (int i = 0; i < 16; ++i) {
        int idx = t + i * 256; int r = idx >> 6, c = idx & 63;
        tile[r][c] = w1[(size_t)(kb + r) * 256 + nb + c];
    }
    __syncthreads();
    #pragma unroll
    for (int i = 0; i < 16; ++i) {
        int idx = t + i * 256; int n = idx >> 6, k = idx & 63;
        w1t[(size_t)(nb + n) * SDIM + kb + k] = __float2bfloat16(tile[k][n]);
    }
}

// ---------------------------------------------------------------------------
// Kernel 2: MFMA GEMM1. C[m][n] = feats(bf16)[m][k] * w1t(bf16)[n][k]^T.
// 128x128 tile, BK=32, split-K=16 -> grid (8,2,16) = 256 blocks, 4 waves each
// owning 64x64 (4x4 frags of 16x16x32). LDS chunk layout per 128-row operand:
// byte(row,kb) = row*64 + ((kb ^ ((row>>1)&3))<<4) — 2-way (free) on b128
// frag reads under the 16-lane-group model. Staging: linear dest, swizzled
// global source (chunk c holds (row=c>>2, kb=(c&3)^((row>>1)&3))).
// C/D layout (m89): col = lane&15, row = (lane>>4)*4 + reg.
// ---------------------------------------------------------------------------
__global__ __launch_bounds__(256) void gemm1_mfma(
    const __hip_bfloat16* __restrict__ A,   // feats (1024, 16384)
    const __hip_bfloat16* __restrict__ B,   // w1t   (256, 16384)
    float* __restrict__ part)               // (16, 1024, 256)
{
    __shared__ char As[8192];
    __shared__ char Bs[8192];
    const int tid  = threadIdx.x;
    const int lane = tid & 63;
    const int wave = tid >> 6;
    const int wm = wave & 1, wn = wave >> 1;
    const int bm = blockIdx.x, bn = blockIdx.y, ks = blockIdx.z;
    const int k0 = ks * 1024;

    // staging: thread handles chunks c0 = tid, c1 = tid + 256 (512 chunks/op)
    const int c0 = tid, c1 = tid + 256;
    const int r0s = c0 >> 2, kb0 = (c0 & 3) ^ ((r0s >> 1) & 3);
    const int r1s = c1 >> 2, kb1 = (c1 & 3) ^ ((r1s >> 1) & 3);
    const __hip_bfloat16* A0 = A + (size_t)(bm * 128 + r0s) * SDIM + k0 + kb0 * 8;
    const __hip_bfloat16* A1 = A + (size_t)(bm * 128 + r1s) * SDIM + k0 + kb1 * 8;
    const __hip_bfloat16* B0 = B + (size_t)(bn * 128 + r0s) * SDIM + k0 + kb0 * 8;
    const __hip_bfloat16* B1 = B + (size_t)(bn * 128 + r1s) * SDIM + k0 + kb1 * 8;

    // frag read bases (row&3-swizzle is mi-invariant: mi*16 ≡ 0 mod 8)
    const int kbx  = lane >> 4;
    const int arow = wm * 64 + (lane & 15);
    const int brow = wn * 64 + (lane & 15);
    const int abase = arow * 64 + ((kbx ^ ((arow >> 1) & 3)) << 4);
    const int bbase = brow * 64 + ((kbx ^ ((brow >> 1) & 3)) << 4);

    f32x4 acc[4][4];
    #pragma unroll
    for (int i = 0; i < 4; ++i)
        #pragma unroll
        for (int j = 0; j < 4; ++j)
            acc[i][j] = (f32x4){0.f, 0.f, 0.f, 0.f};

    uint4 ra0 = *(const uint4*)A0;
    uint4 ra1 = *(const uint4*)A1;
    uint4 rb0 = *(const uint4*)B0;
    uint4 rb1 = *(const uint4*)B1;

    for (int kt = 0; kt < 32; ++kt) {
        *(uint4*)(As + c0 * 16) = ra0;
        *(uint4*)(As + c1 * 16) = ra1;
        *(uint4*)(Bs + c0 * 16) = rb0;
        *(uint4*)(Bs + c1 * 16) = rb1;
        __syncthreads();
        if (kt < 31) {   // prefetch next K-step while MFMAs run
            const int d = (kt + 1) * 32;
            ra0 = *(const uint4*)(A0 + d);
            ra1 = *(const uint4*)(A1 + d);
            rb0 = *(const uint4*)(B0 + d);
            rb1 = *(const uint4*)(B1 + d);
        }
        bf16x8 a[4], b[4];
        #pragma unroll
        for (int mi = 0; mi < 4; ++mi) a[mi] = *(const bf16x8*)(As + abase + mi * 1024);
        #pragma unroll
        for (int ni = 0; ni < 4; ++ni) b[ni] = *(const bf16x8*)(Bs + bbase + ni * 1024);
        #pragma unroll
        for (int mi = 0; mi < 4; ++mi)
            #pragma unroll
            for (int ni = 0; ni < 4; ++ni)
                acc[mi][ni] = __builtin_amdgcn_mfma_f32_16x16x32_bf16(a[mi], b[ni], acc[mi][ni], 0, 0, 0);
        __syncthreads();
    }

    // epilogue: part[ks][m][n]
    float* P = part + ((size_t)ks * NBATCH + bm * 128 + wm * 64) * 256 + bn * 128 + wn * 64;
    const int mrow = (lane >> 4) * 4;
    const int ncol = lane & 15;
    #pragma unroll
    for (int mi = 0; mi < 4; ++mi)
        #pragma unroll
        for (int ni = 0; ni < 4; ++ni) {
            #pragma unroll
            for (int r = 0; r < 4; ++r)
                P[(size_t)(mi * 16 + mrow + r) * 256 + ni * 16 + ncol] = acc[mi][ni][r];
        }
}

// ---------------------------------------------------------------------------
// Kernel 3: reduce split-K partials + bias + relu, then the two small GEMMs.
// ---------------------------------------------------------------------------
__global__ __launch_bounds__(256) void tail_kernel(
    const float* __restrict__ part,  // (16, 1024, 256)
    const float* __restrict__ b1,
    const float* __restrict__ w2,    // (256, 128)
    const float* __restrict__ b2,
    const float* __restrict__ w3,    // (128, 64)
    const float* __restrict__ b3,
    float* __restrict__ out)         // (1024, 64)
{
    __shared__ float h1[256];
    __shared__ float h2[128];
    const int b = blockIdx.x, t = threadIdx.x;

    float s = b1[t];
    #pragma unroll
    for (int sp = 0; sp < KSPLIT; ++sp)
        s += part[((size_t)sp * NBATCH + b) * 256 + t];
    h1[t] = fmaxf(s, 0.f);
    __syncthreads();

    if (t < 128) {
        float acc = b2[t];
        #pragma unroll 4
        for (int k = 0; k < 256; ++k) acc = fmaf(h1[k], w2[k * 128 + t], acc);
        h2[t] = fmaxf(acc, 0.f);
    }
    __syncthreads();

    if (t < 64) {
        float acc = b3[t];
        #pragma unroll 4
        for (int k = 0; k < 128; ++k) acc = fmaf(h2[k], w3[k * 64 + t], acc);
        out[(size_t)b * 64 + t] = acc;
    }
}

// ---------------------------------------------------------------------------
extern "C" void kernel_launch(void* const* d_in, const int* in_sizes, int n_in,
                              void* d_out, int out_size, void* d_ws, size_t ws_size,
                              hipStream_t stream) {
    const float* x   = (const float*)d_in[0];
    const float* ep  = (const float*)d_in[1];
    const float* rp  = (const float*)d_in[2];
    const float* ent = (const float*)d_in[3];
    const float* w1  = (const float*)d_in[4];
    const float* b1  = (const float*)d_in[5];
    const float* w2  = (const float*)d_in[6];
    const float* b2  = (const float*)d_in[7];
    const float* w3  = (const float*)d_in[8];
    const float* b3  = (const float*)d_in[9];
    float* out = (float*)d_out;

    // ws layout: feats bf16 (32 MiB) | w1t bf16 (8 MiB) | part fp32 (16 MiB)
    __hip_bfloat16* feats = (__hip_bfloat16*)d_ws;
    __hip_bfloat16* w1t   = feats + (size_t)NBATCH * SDIM;
    float*          part  = (float*)(w1t + (size_t)256 * SDIM);

    wtr_kernel<<<dim3(256, 4), 256, 0, stream>>>(w1, w1t);
    sim_kernel<<<NBATCH, 1024, 0, stream>>>(x, ep, rp, ent, feats);
    gemm1_mfma<<<dim3(8, 2, KSPLIT), 256, 0, stream>>>(feats, w1t, part);
    tail_kernel<<<NBATCH, 256, 0, stream>>>(part, b1, w2, b2, w3, b3, out);
}